// Round 14
// baseline (765.342 us; speedup 1.0000x reference)
//
#include <hip/hip_runtime.h>
#include <hip/hip_bf16.h>
#include <math.h>

// Problem dims (fixed by reference)
#define D_MODEL 384
#define N_LAYER 8
#define N_MELS  80
#define D_STATE 16
#define D_CONV  4
#define D_INNER 768
#define DT_RANK 24
#define BB      4
#define LL      512
#define MTOK    (BB*LL)   // 2048

#define BMt 64
#define BNt 64
#define BKt 16

#define XP_N   56
#define XPS    12           // split-K splits for x-proj
#define XPKC   64           // K per split

typedef __attribute__((ext_vector_type(8))) short bf16x8;
typedef __attribute__((ext_vector_type(4))) short bf16x4;
typedef __attribute__((ext_vector_type(4))) float f32x4;

__device__ __forceinline__ float silu_f(float x) { return x / (1.f + __expf(-x)); }
__device__ __forceinline__ short bf_raw(float x) {
  __hip_bfloat16 h = __float2bfloat16(x);
  return *reinterpret_cast<short*>(&h);
}
__device__ __forceinline__ float bfu(unsigned short u) {
  unsigned v = ((unsigned)u) << 16;
  return *reinterpret_cast<float*>(&v);
}

// ---------------------------------------------------------------------------
// Generic tiled fp32 GEMM (edge ops only): C[M,N] = A[M,K] @ W[K,N]
// EPI: 0 none, 1 +bias
// ---------------------------------------------------------------------------
template<int EPI>
__global__ __launch_bounds__(256) void gemm_f32(
    const float* __restrict__ A, int lda,
    const float* __restrict__ W, int ldw,
    const float* __restrict__ bias,
    float* __restrict__ C, int ldc,
    int M, int N, int K)
{
  __shared__ float As[BKt][BMt];
  __shared__ float Ws[BKt][BNt];
  const int tid = threadIdx.x;
  const int tx = tid & 15, ty = tid >> 4;
  const int m0 = blockIdx.y * BMt, n0 = blockIdx.x * BNt;
  const int am = tid >> 2, ak4 = (tid & 3) << 2;
  const int wk = tid >> 4, wn4 = (tid & 15) << 2;

  float acc[4][4] = {};

  for (int k0 = 0; k0 < K; k0 += BKt) {
    float4 va = make_float4(0.f, 0.f, 0.f, 0.f);
    {
      int m = m0 + am;
      if (m < M) {
        if (k0 + ak4 + 3 < K) {
          va = *reinterpret_cast<const float4*>(&A[(size_t)m * lda + k0 + ak4]);
        } else {
          float t[4];
          #pragma unroll
          for (int j = 0; j < 4; ++j)
            t[j] = (k0 + ak4 + j < K) ? A[(size_t)m * lda + k0 + ak4 + j] : 0.f;
          va = make_float4(t[0], t[1], t[2], t[3]);
        }
      }
    }
    As[ak4 + 0][am] = va.x;
    As[ak4 + 1][am] = va.y;
    As[ak4 + 2][am] = va.z;
    As[ak4 + 3][am] = va.w;

    float4 vw = make_float4(0.f, 0.f, 0.f, 0.f);
    {
      int kw = k0 + wk;
      if (kw < K) {
        if (n0 + wn4 + 3 < N) {
          vw = *reinterpret_cast<const float4*>(&W[(size_t)kw * ldw + n0 + wn4]);
        } else {
          float t[4];
          #pragma unroll
          for (int j = 0; j < 4; ++j)
            t[j] = (n0 + wn4 + j < N) ? W[(size_t)kw * ldw + n0 + wn4 + j] : 0.f;
          vw = make_float4(t[0], t[1], t[2], t[3]);
        }
      }
    }
    *reinterpret_cast<float4*>(&Ws[wk][wn4]) = vw;

    __syncthreads();
    #pragma unroll
    for (int kk = 0; kk < BKt; ++kk) {
      const float4 a4 = *reinterpret_cast<const float4*>(&As[kk][ty << 2]);
      const float4 w4 = *reinterpret_cast<const float4*>(&Ws[kk][tx << 2]);
      float av[4] = {a4.x, a4.y, a4.z, a4.w};
      float wv[4] = {w4.x, w4.y, w4.z, w4.w};
      #pragma unroll
      for (int i = 0; i < 4; ++i)
        #pragma unroll
        for (int j = 0; j < 4; ++j)
          acc[i][j] += av[i] * wv[j];
    }
    __syncthreads();
  }

  #pragma unroll
  for (int i = 0; i < 4; ++i) {
    int row = m0 + (ty << 2) + i;
    if (row >= M) continue;
    #pragma unroll
    for (int j = 0; j < 4; ++j) {
      int col = n0 + (tx << 2) + j;
      if (col >= N) continue;
      float v = acc[i][j];
      if (EPI == 1) v += bias[col];
      C[(size_t)row * ldc + col] = v;
    }
  }
}

// ---------------------------------------------------------------------------
// bf16 MFMA GEMM: A_bf16[M,K] @ WT_bf16[N,K] -> f32 C (EPI 0/3) or bf16 Cb
// (OBF=1). M,N,K multiples of 64.
// ---------------------------------------------------------------------------
template<int EPI, int OBF>
__global__ __launch_bounds__(256) void gemm_bf16(
    const __hip_bfloat16* __restrict__ A,   // [M][K]
    const __hip_bfloat16* __restrict__ WT,  // [N][K]
    const float* __restrict__ resid,
    float* __restrict__ C,
    __hip_bfloat16* __restrict__ Cb,
    int ldc, int M, int N, int K)
{
  __shared__ __align__(16) __hip_bfloat16 Asl[64][72];
  __shared__ __align__(16) __hip_bfloat16 Bsl[64][72];
  const int tid = threadIdx.x;
  const int wave = tid >> 6, lane = tid & 63;
  const int m0 = blockIdx.y * 64, n0 = blockIdx.x * 64;
  const int lrow = tid >> 2;
  const int lk   = (tid & 3) << 4;
  const int g16 = lane >> 4;
  const int l16 = lane & 15;

  f32x4 acc[4] = {};

  for (int k0 = 0; k0 < K; k0 += 64) {
    const uint4* ga = reinterpret_cast<const uint4*>(&A[(size_t)(m0 + lrow) * K + k0 + lk]);
    uint4* la = reinterpret_cast<uint4*>(&Asl[lrow][lk]);
    la[0] = ga[0]; la[1] = ga[1];
    const uint4* gb = reinterpret_cast<const uint4*>(&WT[(size_t)(n0 + lrow) * K + k0 + lk]);
    uint4* lb = reinterpret_cast<uint4*>(&Bsl[lrow][lk]);
    lb[0] = gb[0]; lb[1] = gb[1];
    __syncthreads();
    #pragma unroll
    for (int kk = 0; kk < 64; kk += 32) {
      bf16x8 a = *reinterpret_cast<const bf16x8*>(&Asl[wave * 16 + l16][kk + g16 * 8]);
      #pragma unroll
      for (int f = 0; f < 4; ++f) {
        bf16x8 b = *reinterpret_cast<const bf16x8*>(&Bsl[f * 16 + l16][kk + g16 * 8]);
        acc[f] = __builtin_amdgcn_mfma_f32_16x16x32_bf16(a, b, acc[f], 0, 0, 0);
      }
    }
    __syncthreads();
  }

  #pragma unroll
  for (int f = 0; f < 4; ++f) {
    #pragma unroll
    for (int r = 0; r < 4; ++r) {
      int row = m0 + wave * 16 + g16 * 4 + r;
      int col = n0 + f * 16 + l16;
      float v = acc[f][r];
      if (EPI == 3) v += resid[(size_t)row * ldc + col];
      if (OBF) Cb[(size_t)row * ldc + col] = __float2bfloat16(v);
      else     C[(size_t)row * ldc + col] = v;
    }
  }
}

// ---------------------------------------------------------------------------
// Batched bf16 MFMA GEMM (attention): per-z strides. C = A @ WT^T, f32 out.
// ---------------------------------------------------------------------------
__global__ __launch_bounds__(256) void gemm_bf16_bat(
    const __hip_bfloat16* __restrict__ A, size_t sA,
    const __hip_bfloat16* __restrict__ WT, size_t sW,
    float* __restrict__ C, size_t sC,
    int M, int N, int K)
{
  A  += (size_t)blockIdx.z * sA;
  WT += (size_t)blockIdx.z * sW;
  C  += (size_t)blockIdx.z * sC;
  __shared__ __align__(16) __hip_bfloat16 Asl[64][72];
  __shared__ __align__(16) __hip_bfloat16 Bsl[64][72];
  const int tid = threadIdx.x;
  const int wave = tid >> 6, lane = tid & 63;
  const int m0 = blockIdx.y * 64, n0 = blockIdx.x * 64;
  const int lrow = tid >> 2;
  const int lk   = (tid & 3) << 4;
  const int g16 = lane >> 4;
  const int l16 = lane & 15;

  f32x4 acc[4] = {};

  for (int k0 = 0; k0 < K; k0 += 64) {
    const uint4* ga = reinterpret_cast<const uint4*>(&A[(size_t)(m0 + lrow) * K + k0 + lk]);
    uint4* la = reinterpret_cast<uint4*>(&Asl[lrow][lk]);
    la[0] = ga[0]; la[1] = ga[1];
    const uint4* gb = reinterpret_cast<const uint4*>(&WT[(size_t)(n0 + lrow) * K + k0 + lk]);
    uint4* lb = reinterpret_cast<uint4*>(&Bsl[lrow][lk]);
    lb[0] = gb[0]; lb[1] = gb[1];
    __syncthreads();
    #pragma unroll
    for (int kk = 0; kk < 64; kk += 32) {
      bf16x8 a = *reinterpret_cast<const bf16x8*>(&Asl[wave * 16 + l16][kk + g16 * 8]);
      #pragma unroll
      for (int f = 0; f < 4; ++f) {
        bf16x8 b = *reinterpret_cast<const bf16x8*>(&Bsl[f * 16 + l16][kk + g16 * 8]);
        acc[f] = __builtin_amdgcn_mfma_f32_16x16x32_bf16(a, b, acc[f], 0, 0, 0);
      }
    }
    __syncthreads();
  }

  #pragma unroll
  for (int f = 0; f < 4; ++f) {
    #pragma unroll
    for (int r = 0; r < 4; ++r) {
      int row = m0 + wave * 16 + g16 * 4 + r;
      int col = n0 + f * 16 + l16;
      C[(size_t)row * N + col] = acc[f][r];
    }
  }
}

// ---------------------------------------------------------------------------
// Split-K x-proj with FUSED depthwise conv + SiLU.
// A tile [64 m-rows][64 d-cols slice] computed on the fly from xr:
//   xs[m][d] = silu(cb[d] + sum_k xr[m-3+k][d] * cw[d][k])
// Each xs element computed exactly once across the split grid.
// part[s][M][64] = xs[:, s*64:(s+1)*64] @ xpT rows.
// ---------------------------------------------------------------------------
__global__ __launch_bounds__(256) void xproj_conv_splitk(
    const __hip_bfloat16* __restrict__ xrb,  // [M][1536] bf16 (cols 0..768 = conv in)
    const float* __restrict__ cw,            // [768][4] layer slice
    const float* __restrict__ cb,            // [768]
    const __hip_bfloat16* __restrict__ WT,   // [64][768] padded xprojT slice
    float* __restrict__ part)                // [XPS][M][64]
{
  __shared__ __align__(16) __hip_bfloat16 Asl[64][72];
  __shared__ __align__(16) __hip_bfloat16 Bsl[64][72];
  const int tid = threadIdx.x;
  const int wave = tid >> 6, lane = tid & 63;
  const int split = blockIdx.x;
  const int m0 = blockIdx.y * 64;
  const int kbase = split * XPKC;
  const int lrow = tid >> 2;
  const int lk   = (tid & 3) << 4;
  const int g16 = lane >> 4;
  const int l16 = lane & 15;

  // --- fused conv+silu A-tile staging ---
  {
    const int m = m0 + lrow;
    const int b = m >> 9, l = m & 511;
    const int dcol0 = kbase + lk;
    unsigned wrow[4][8];
    #pragma unroll
    for (int k = 0; k < 4; ++k) {
      int t = l - 3 + k;
      if (t >= 0) {
        const uint4* p = reinterpret_cast<const uint4*>(
            &xrb[((size_t)(b * LL + t)) * (2 * D_INNER) + dcol0]);
        uint4 q0 = p[0], q1 = p[1];
        wrow[k][0] = q0.x; wrow[k][1] = q0.y; wrow[k][2] = q0.z; wrow[k][3] = q0.w;
        wrow[k][4] = q1.x; wrow[k][5] = q1.y; wrow[k][6] = q1.z; wrow[k][7] = q1.w;
      } else {
        #pragma unroll
        for (int w = 0; w < 8; ++w) wrow[k][w] = 0u;
      }
    }
    #pragma unroll
    for (int j = 0; j < 16; ++j) {
      float4 cw4 = *reinterpret_cast<const float4*>(&cw[(size_t)(dcol0 + j) * 4]);
      float cwa[4] = {cw4.x, cw4.y, cw4.z, cw4.w};
      float a = cb[dcol0 + j];
      #pragma unroll
      for (int k = 0; k < 4; ++k) {
        unsigned w = wrow[k][j >> 1];
        unsigned short hv = (j & 1) ? (unsigned short)(w >> 16) : (unsigned short)(w & 0xffff);
        a += bfu(hv) * cwa[k];
      }
      Asl[lrow][lk + j] = __float2bfloat16(silu_f(a));
    }
  }

  const uint4* gb = reinterpret_cast<const uint4*>(&WT[(size_t)lrow * D_INNER + kbase + lk]);
  uint4* lb = reinterpret_cast<uint4*>(&Bsl[lrow][lk]);
  lb[0] = gb[0]; lb[1] = gb[1];
  __syncthreads();

  f32x4 acc[4] = {};
  #pragma unroll
  for (int kk = 0; kk < 64; kk += 32) {
    bf16x8 a = *reinterpret_cast<const bf16x8*>(&Asl[wave * 16 + l16][kk + g16 * 8]);
    #pragma unroll
    for (int f = 0; f < 4; ++f) {
      bf16x8 b = *reinterpret_cast<const bf16x8*>(&Bsl[f * 16 + l16][kk + g16 * 8]);
      acc[f] = __builtin_amdgcn_mfma_f32_16x16x32_bf16(a, b, acc[f], 0, 0, 0);
    }
  }

  #pragma unroll
  for (int f = 0; f < 4; ++f) {
    #pragma unroll
    for (int r = 0; r < 4; ++r) {
      int row = m0 + wave * 16 + g16 * 4 + r;
      int col = f * 16 + l16;
      part[((size_t)split * MTOK + row) * 64 + col] = acc[f][r];
    }
  }
}

__global__ __launch_bounds__(256) void xproj_reduce_kernel(
    const float* __restrict__ part, float* __restrict__ xdbl)
{
  int idx = blockIdx.x * 256 + threadIdx.x;
  if (idx >= MTOK * XP_N) return;
  int m = idx / XP_N, col = idx - m * XP_N;
  float s = 0.f;
  #pragma unroll
  for (int p = 0; p < XPS; ++p)
    s += part[((size_t)p * MTOK + m) * 64 + col];
  xdbl[idx] = s;
}

// ---------------------------------------------------------------------------
// Weight convert + transpose: src f32 [L][K][N] -> dst bf16 [L][N][K]
// ---------------------------------------------------------------------------
__global__ __launch_bounds__(256) void wconv_t_kernel(
    const float* __restrict__ src, __hip_bfloat16* __restrict__ dst,
    int K, int N, size_t ldl)
{
  __shared__ float tile[32][33];
  int l = blockIdx.z;
  int kb = blockIdx.y * 32, nb = blockIdx.x * 32;
  int tn = threadIdx.x & 31, tk = threadIdx.x >> 5;  // 32 x 8
  const float* s = src + (size_t)l * K * N;
  __hip_bfloat16* dd = dst + (size_t)l * ldl;
  #pragma unroll
  for (int i = 0; i < 4; ++i) {
    int k = kb + tk + i * 8, n = nb + tn;
    tile[tk + i * 8][tn] = (k < K && n < N) ? s[(size_t)k * N + n] : 0.f;
  }
  __syncthreads();
  #pragma unroll
  for (int i = 0; i < 4; ++i) {
    int n = nb + tk + i * 8, k = kb + tn;
    if (n < N && k < K) dd[(size_t)n * K + k] = __float2bfloat16(tile[tn][tk + i * 8]);
  }
}

// ---------------------------------------------------------------------------
// f32 -> bf16 elementwise convert (n multiple of 4)
// ---------------------------------------------------------------------------
__global__ __launch_bounds__(256) void f2b_kernel(
    const float* __restrict__ src, __hip_bfloat16* __restrict__ dst, int n)
{
  int i = (blockIdx.x * 256 + threadIdx.x) * 4;
  if (i >= n) return;
  float4 v = *reinterpret_cast<const float4*>(&src[i]);
  bf16x4 o;
  o[0] = bf_raw(v.x); o[1] = bf_raw(v.y); o[2] = bf_raw(v.z); o[3] = bf_raw(v.w);
  *reinterpret_cast<bf16x4*>(&dst[i]) = o;
}

// ---------------------------------------------------------------------------
// Row softmax: scores f32 [R][512] -> P bf16 [R][512]; one wave per row.
// ---------------------------------------------------------------------------
__global__ __launch_bounds__(256) void softmax_rows_kernel(
    const float* __restrict__ scores, __hip_bfloat16* __restrict__ P)
{
  int row = (blockIdx.x * 256 + threadIdx.x) >> 6;
  int lane = threadIdx.x & 63;
  if (row >= BB * LL) return;
  const float* s = scores + (size_t)row * LL + lane * 8;
  float4 v0 = *reinterpret_cast<const float4*>(s);
  float4 v1 = *reinterpret_cast<const float4*>(s + 4);
  float mx = fmaxf(fmaxf(fmaxf(v0.x, v0.y), fmaxf(v0.z, v0.w)),
                   fmaxf(fmaxf(v1.x, v1.y), fmaxf(v1.z, v1.w)));
  #pragma unroll
  for (int off = 32; off; off >>= 1) mx = fmaxf(mx, __shfl_xor(mx, off, 64));
  float e[8];
  e[0] = __expf(v0.x - mx); e[1] = __expf(v0.y - mx);
  e[2] = __expf(v0.z - mx); e[3] = __expf(v0.w - mx);
  e[4] = __expf(v1.x - mx); e[5] = __expf(v1.y - mx);
  e[6] = __expf(v1.z - mx); e[7] = __expf(v1.w - mx);
  float sum = ((e[0] + e[1]) + (e[2] + e[3])) + ((e[4] + e[5]) + (e[6] + e[7]));
  #pragma unroll
  for (int off = 32; off; off >>= 1) sum += __shfl_xor(sum, off, 64);
  float inv = 1.f / sum;
  bf16x8 o;
  #pragma unroll
  for (int j = 0; j < 8; ++j) o[j] = bf_raw(e[j] * inv);
  *reinterpret_cast<bf16x8*>(&P[(size_t)row * LL + lane * 8]) = o;
}

// ---------------------------------------------------------------------------
// RMSNorm: one wave per row; fp32 output optional
// ---------------------------------------------------------------------------
__global__ __launch_bounds__(256) void rmsnorm_kernel(
    const float* __restrict__ x, const float* __restrict__ w,
    float* __restrict__ out, __hip_bfloat16* __restrict__ outb, int M, int N)
{
  int gw = (blockIdx.x * blockDim.x + threadIdx.x) >> 6;
  int lane = threadIdx.x & 63;
  if (gw >= M) return;
  const float* row = x + (size_t)gw * N;
  float ss = 0.f;
  for (int j = lane; j < N; j += 64) { float v = row[j]; ss += v * v; }
  #pragma unroll
  for (int off = 32; off; off >>= 1) ss += __shfl_xor(ss, off, 64);
  float scale = rsqrtf(ss / (float)N + 1e-5f);
  float* orow = out ? out + (size_t)gw * N : nullptr;
  __hip_bfloat16* brow = outb + (size_t)gw * N;
  for (int j = lane; j < N; j += 64) {
    float v = row[j] * scale * w[j];
    if (orow) orow[j] = v;
    brow[j] = __float2bfloat16(v);
  }
}

// ---------------------------------------------------------------------------
// Chunked parallel selective scan v9 = v8 + fused conv+SiLU in staging
// (u computed from xr directly; xs buffer eliminated). Same LDS (39,872B),
// same phases/swizzle as v8.
// ---------------------------------------------------------------------------
#define SC6_T  16
#define SC6_NC 32
__global__ __launch_bounds__(512) void scan_kernel9(
    const __hip_bfloat16* __restrict__ xrb, // M x 1536 bf16 (conv in cols 0..768, res cols 768..)
    const float* __restrict__ xdbl,   // M x 56 (dt|B|C)
    const float* __restrict__ A_log,  // 768 x 16 (layer slice)
    const float* __restrict__ Dp,     // 768
    const float* __restrict__ dtw,    // [24][768] layer slice
    const float* __restrict__ dtb,    // [768] layer slice
    const float* __restrict__ cw,     // [768][4] layer slice
    const float* __restrict__ cb,     // [768]
    __hip_bfloat16* __restrict__ yg)  // M x 768 bf16
{
  __shared__ float sdelta[2][LL];
  __shared__ unsigned supk[LL];            // packed bf16 pair (u_d0, u_d1)
  __shared__ float sdw[2][DT_RANK];
  __shared__ float sP[2][SC6_NC][D_STATE + 1];
  __shared__ float sS[2][SC6_NC][D_STATE + 1];
  __shared__ float sH0[2][SC6_NC][D_STATE + 1];
  __shared__ float sY[2][LL][5];

  const int id = blockIdx.x;
  const int r  = id / 48;        // 0..31
  const int G  = id % 48;        // id%8 == G%8
  const int b  = G / 12;         // 0..3
  const int q  = G % 12;
  const int d0 = q * 64 + 2 * r;
  const int d1 = d0 + 1;

  const int tid = threadIdx.x;   // 0..511
  const int n = tid & 15;
  const int c = tid >> 4;        // 0..31

  if (tid < DT_RANK) {
    sdw[0][tid] = dtw[tid * D_INNER + d0];
    sdw[1][tid] = dtw[tid * D_INNER + d1];
  }
  __syncthreads();

  // staging: one l per thread; dt-proj dot + FUSED conv+silu for u
  {
    const int l = tid;
    const size_t m = (size_t)(b * LL + l);
    float acc0 = dtb[d0], acc1 = dtb[d1];
    const float* xrow = &xdbl[m * 56];
    #pragma unroll
    for (int k4 = 0; k4 < DT_RANK; k4 += 4) {
      float4 xv = *reinterpret_cast<const float4*>(&xrow[k4]);
      acc0 += xv.x * sdw[0][k4] + xv.y * sdw[0][k4 + 1] + xv.z * sdw[0][k4 + 2] + xv.w * sdw[0][k4 + 3];
      acc1 += xv.x * sdw[1][k4] + xv.y * sdw[1][k4 + 1] + xv.z * sdw[1][k4 + 2] + xv.w * sdw[1][k4 + 3];
    }
    sdelta[0][l] = (acc0 > 20.f) ? acc0 : log1pf(__expf(acc0));
    sdelta[1][l] = (acc1 > 20.f) ? acc1 : log1pf(__expf(acc1));

    // conv+silu: u[l][d0], u[l][d1] from xr cols d0,d1 rows l-3..l
    float4 cw0 = *reinterpret_cast<const float4*>(&cw[(size_t)d0 * 4]);
    float4 cw1 = *reinterpret_cast<const float4*>(&cw[(size_t)d1 * 4]);
    float cwa0[4] = {cw0.x, cw0.y, cw0.z, cw0.w};
    float cwa1[4] = {cw1.x, cw1.y, cw1.z, cw1.w};
    float u0 = cb[d0], u1 = cb[d1];
    #pragma unroll
    for (int k = 0; k < 4; ++k) {
      int t = l - 3 + k;
      if (t >= 0) {
        unsigned w = *reinterpret_cast<const unsigned*>(
            &xrb[((size_t)(b * LL + t)) * (2 * D_INNER) + d0]);
        u0 += bfu((unsigned short)(w & 0xffff)) * cwa0[k];
        u1 += bfu((unsigned short)(w >> 16)) * cwa1[k];
      }
    }
    unsigned pk = ((unsigned)(unsigned short)bf_raw(silu_f(u0))) |
                  (((unsigned)(unsigned short)bf_raw(silu_f(u1))) << 16);
    supk[l] = pk;
  }

  const float Aval0 = -__expf(A_log[d0 * D_STATE + n]);
  const float Aval1 = -__expf(A_log[d1 * D_STATE + n]);
  const int l0 = c * SC6_T;
  const size_t mbase = (size_t)(b * LL + l0);

  // B prefetch: 16 loads shared by both d's
  float Bv_s[SC6_T];
  #pragma unroll
  for (int t = 0; t < SC6_T; ++t)
    Bv_s[t] = xdbl[(mbase + t) * 56 + DT_RANK + n];

  __syncthreads();

  // Phase 1: per-chunk affine composition for both d's; stash a only
  float a_s[2][SC6_T];
  {
    float P0 = 1.f, S0 = 0.f, P1 = 1.f, S1 = 0.f;
    #pragma unroll
    for (int t = 0; t < SC6_T; ++t) {
      int l = l0 + t;
      unsigned uu = supk[l];
      float uv0 = bfu((unsigned short)(uu & 0xffff));
      float uv1 = bfu((unsigned short)(uu >> 16));
      float dv0 = sdelta[0][l];
      float dv1 = sdelta[1][l];
      float a0 = __expf(dv0 * Aval0);
      float a1 = __expf(dv1 * Aval1);
      P0 *= a0; S0 = a0 * S0 + (dv0 * Bv_s[t]) * uv0;
      P1 *= a1; S1 = a1 * S1 + (dv1 * Bv_s[t]) * uv1;
      a_s[0][t] = a0; a_s[1][t] = a1;
    }
    sP[0][c][n] = P0; sS[0][c][n] = S0;
    sP[1][c][n] = P1; sS[1][c][n] = S1;
  }

  // C prefetch: loads fly during phase 2 + barriers
  float Cv_s[SC6_T];
  #pragma unroll
  for (int t = 0; t < SC6_T; ++t)
    Cv_s[t] = xdbl[(mbase + t) * 56 + DT_RANK + D_STATE + n];

  __syncthreads();

  // Phase 2: Kogge-Stone over 32 chunks, both d's, all 512 threads
  {
    const int c2 = tid & 31;
    const int n2 = tid >> 5;
    #pragma unroll
    for (int dd = 0; dd < 2; ++dd) {
      float p = sP[dd][c2][n2];
      float s = sS[dd][c2][n2];
      #pragma unroll
      for (int k = 1; k <= 16; k <<= 1) {
        float pp = __shfl_up(p, k, 64);
        float sp = __shfl_up(s, k, 64);
        if (c2 >= k) { s = p * sp + s; p = p * pp; }
      }
      if (c2 == 0) sH0[dd][0][n2] = 0.f;
      if (c2 < 31) sH0[dd][c2 + 1][n2] = s;
    }
  }
  __syncthreads();

  // Phase 3: dual replay; dbu recomputed from LDS; 2-shfl partial reduce
  {
    float h0 = sH0[0][c][n];
    float h1 = sH0[1][c][n];
    #pragma unroll
    for (int t = 0; t < SC6_T; ++t) {
      int l = l0 + t;
      unsigned uu = supk[l];
      float uv0 = bfu((unsigned short)(uu & 0xffff));
      float uv1 = bfu((unsigned short)(uu >> 16));
      float dv0 = sdelta[0][l];
      float dv1 = sdelta[1][l];
      h0 = a_s[0][t] * h0 + (dv0 * Bv_s[t]) * uv0;
      h1 = a_s[1][t] * h1 + (dv1 * Bv_s[t]) * uv1;
      float c0 = h0 * Cv_s[t];
      float c1 = h1 * Cv_s[t];
      c0 += __shfl_xor(c0, 1, 64); c0 += __shfl_xor(c0, 2, 64);
      c1 += __shfl_xor(c1, 1, 64); c1 += __shfl_xor(c1, 2, 64);
      if ((n & 3) == 0) { sY[0][l][n >> 2] = c0; sY[1][l][n >> 2] = c1; }
    }
  }
  __syncthreads();

  // Final: one l per thread — both d's, paired bf16 gate read + packed write
  {
    const int l = tid;
    const size_t m = (size_t)(b * LL + l);
    unsigned uu = supk[l];
    float uv0 = bfu((unsigned short)(uu & 0xffff));
    float uv1 = bfu((unsigned short)(uu >> 16));
    float y0 = (sY[0][l][0] + sY[0][l][1]) + (sY[0][l][2] + sY[0][l][3]) + uv0 * Dp[d0];
    float y1 = (sY[1][l][0] + sY[1][l][1]) + (sY[1][l][2] + sY[1][l][3]) + uv1 * Dp[d1];
    unsigned rr = *reinterpret_cast<const unsigned*>(&xrb[m * (2 * D_INNER) + D_INNER + d0]);
    float r0 = bfu((unsigned short)(rr & 0xffff));
    float r1 = bfu((unsigned short)(rr >> 16));
    y0 *= silu_f(r0);
    y1 *= silu_f(r1);
    unsigned outw = ((unsigned)(unsigned short)bf_raw(y0)) |
                    (((unsigned)(unsigned short)bf_raw(y1)) << 16);
    *reinterpret_cast<unsigned*>(&yg[m * D_INNER + d0]) = outw;
  }
}

// ---------------------------------------------------------------------------
extern "C" void kernel_launch(void* const* d_in, const int* in_sizes, int n_in,
                              void* d_out, int out_size, void* d_ws, size_t ws_size,
                              hipStream_t stream) {
  const float* x        = (const float*)d_in[0];
  const float* enc      = (const float*)d_in[1];
  const float* w_in     = (const float*)d_in[2];
  const float* b_in     = (const float*)d_in[3];
  const float* ln_w     = (const float*)d_in[4];
  const float* inproj_w = (const float*)d_in[5];
  const float* conv_w   = (const float*)d_in[6];
  const float* conv_b   = (const float*)d_in[7];
  const float* xproj_w  = (const float*)d_in[8];
  const float* dtproj_w = (const float*)d_in[9];
  const float* dtproj_b = (const float*)d_in[10];
  const float* A_log    = (const float*)d_in[11];
  const float* Dvec     = (const float*)d_in[12];
  const float* outproj_w= (const float*)d_in[13];
  const float* normf_w  = (const float*)d_in[14];
  const float* w_out    = (const float*)d_in[15];

  float* ws = (float*)d_ws;
  float* h     = ws; ws += MTOK * D_MODEL;
  float* hn    = ws; ws += MTOK * D_MODEL;
  float* xdbl  = ws; ws += MTOK * XP_N;
  float* xpart = ws; ws += XPS * MTOK * 64;
  float* h2    = ws; ws += MTOK * D_MODEL;
  float* scores= ws; ws += BB * LL * LL;
  __hip_bfloat16* xr_bf = (__hip_bfloat16*)ws; ws += MTOK * 2 * D_INNER / 2;
  __hip_bfloat16* hn_bf = (__hip_bfloat16*)ws; ws += MTOK * D_MODEL / 2;
  __hip_bfloat16* yg_bf = (__hip_bfloat16*)ws; ws += MTOK * D_INNER / 2;
  __hip_bfloat16* h_bf  = (__hip_bfloat16*)ws; ws += MTOK * D_MODEL / 2;
  __hip_bfloat16* P_bf  = (__hip_bfloat16*)ws; ws += BB * LL * LL / 2;
  __hip_bfloat16* enc_bf= (__hip_bfloat16*)ws; ws += BB * LL * D_MODEL / 2;
  __hip_bfloat16* encT  = (__hip_bfloat16*)ws; ws += BB * LL * D_MODEL / 2;
  __hip_bfloat16* WinT  = (__hip_bfloat16*)ws; ws += N_LAYER * D_MODEL * 2 * D_INNER / 2;
  __hip_bfloat16* WoutT = (__hip_bfloat16*)ws; ws += N_LAYER * D_INNER * D_MODEL / 2;
  __hip_bfloat16* XpT   = (__hip_bfloat16*)ws; ws += N_LAYER * 64 * D_INNER / 2;

  dim3 blk256(256), blk512(512);

  // Prologue: weight conversions
  wconv_t_kernel<<<dim3(2 * D_INNER / 32, D_MODEL / 32, N_LAYER), blk256, 0, stream>>>(
      inproj_w, WinT, D_MODEL, 2 * D_INNER, (size_t)2 * D_INNER * D_MODEL);
  wconv_t_kernel<<<dim3(D_MODEL / 32, D_INNER / 32, N_LAYER), blk256, 0, stream>>>(
      outproj_w, WoutT, D_INNER, D_MODEL, (size_t)D_MODEL * D_INNER);
  wconv_t_kernel<<<dim3((XP_N + 31) / 32, D_INNER / 32, N_LAYER), blk256, 0, stream>>>(
      xproj_w, XpT, D_INNER, XP_N, (size_t)64 * D_INNER);
  // enc conversions for attention
  f2b_kernel<<<(BB * LL * D_MODEL / 4 + 255) / 256, blk256, 0, stream>>>(
      enc, enc_bf, BB * LL * D_MODEL);
  wconv_t_kernel<<<dim3(D_MODEL / 32, LL / 32, BB), blk256, 0, stream>>>(
      enc, encT, LL, D_MODEL, (size_t)D_MODEL * LL);

  // input projection: h = x @ w_in + b_in  (fp32)
  gemm_f32<1><<<dim3(D_MODEL / BNt, MTOK / BMt), blk256, 0, stream>>>(
      x, N_MELS, w_in, D_MODEL, b_in, h, D_MODEL, MTOK, D_MODEL, N_MELS);

  auto mamba = [&](float* hcur, int i) {
    rmsnorm_kernel<<<MTOK * 64 / 256, blk256, 0, stream>>>(
        hcur, ln_w + (size_t)i * D_MODEL, nullptr, hn_bf, MTOK, D_MODEL);
    // in-proj (bf16 MFMA) -> bf16 xr
    gemm_bf16<0, 1><<<dim3(2 * D_INNER / 64, MTOK / 64), blk256, 0, stream>>>(
        hn_bf, WinT + (size_t)i * D_MODEL * 2 * D_INNER, nullptr,
        nullptr, xr_bf, 2 * D_INNER, MTOK, 2 * D_INNER, D_MODEL);
    // x-proj with fused conv+silu
    xproj_conv_splitk<<<dim3(XPS, MTOK / 64), blk256, 0, stream>>>(
        xr_bf, conv_w + (size_t)i * D_INNER * D_CONV, conv_b + (size_t)i * D_INNER,
        XpT + (size_t)i * 64 * D_INNER, xpart);
    xproj_reduce_kernel<<<(MTOK * XP_N + 255) / 256, blk256, 0, stream>>>(xpart, xdbl);
    // scan with fused conv+silu for u
    scan_kernel9<<<BB * D_INNER / 2, blk512, 0, stream>>>(
        xr_bf, xdbl, A_log + (size_t)i * D_INNER * D_STATE, Dvec + (size_t)i * D_INNER,
        dtproj_w + (size_t)i * DT_RANK * D_INNER, dtproj_b + (size_t)i * D_INNER,
        conv_w + (size_t)i * D_INNER * D_CONV, conv_b + (size_t)i * D_INNER,
        yg_bf);
    gemm_bf16<3, 0><<<dim3(D_MODEL / 64, MTOK / 64), blk256, 0, stream>>>(
        yg_bf, WoutT + (size_t)i * D_INNER * D_MODEL, hcur,
        hcur, nullptr, D_MODEL, MTOK, D_MODEL, D_INNER);
  };

  for (int i = 0; i < N_LAYER / 2; ++i) mamba(h, i);

  // ---- attention via MFMA ----
  f2b_kernel<<<(MTOK * D_MODEL / 4 + 255) / 256, blk256, 0, stream>>>(
      h, h_bf, MTOK * D_MODEL);
  gemm_bf16_bat<<<dim3(LL / 64, LL / 64, BB), blk256, 0, stream>>>(
      h_bf, (size_t)LL * D_MODEL, enc_bf, (size_t)LL * D_MODEL,
      scores, (size_t)LL * LL, LL, LL, D_MODEL);
  softmax_rows_kernel<<<(BB * LL * 64) / 256, blk256, 0, stream>>>(scores, P_bf);
  gemm_bf16_bat<<<dim3(D_MODEL / 64, LL / 64, BB), blk256, 0, stream>>>(
      P_bf, (size_t)LL * LL, encT, (size_t)D_MODEL * LL,
      h2, (size_t)LL * D_MODEL, LL, D_MODEL, LL);

  for (int i = N_LAYER / 2; i < N_LAYER; ++i) mamba(h2, i);

  rmsnorm_kernel<<<MTOK * 64 / 256, blk256, 0, stream>>>(h2, normf_w, hn, hn_bf, MTOK, D_MODEL);
  gemm_f32<0><<<dim3((N_MELS + BNt - 1) / BNt, MTOK / BMt), blk256, 0, stream>>>(
      hn, D_MODEL, w_out, N_MELS, nullptr, (float*)d_out, N_MELS, MTOK, N_MELS, D_MODEL);
}

// Round 15
// 714.042 us; speedup vs baseline: 1.0718x; 1.0718x over previous
//
#include <hip/hip_runtime.h>
#include <hip/hip_bf16.h>
#include <math.h>

// Problem dims (fixed by reference)
#define D_MODEL 384
#define N_LAYER 8
#define N_MELS  80
#define D_STATE 16
#define D_CONV  4
#define D_INNER 768
#define DT_RANK 24
#define BB      4
#define LL      512
#define MTOK    (BB*LL)   // 2048

#define BMt 64
#define BNt 64
#define BKt 16

#define XP_N   56
#define XPS    12           // split-K splits for x-proj
#define XPKC   64           // K per split

typedef __attribute__((ext_vector_type(8))) short bf16x8;
typedef __attribute__((ext_vector_type(4))) short bf16x4;
typedef __attribute__((ext_vector_type(4))) float f32x4;

__device__ __forceinline__ float silu_f(float x) { return x / (1.f + __expf(-x)); }
__device__ __forceinline__ short bf_raw(float x) {
  __hip_bfloat16 h = __float2bfloat16(x);
  return *reinterpret_cast<short*>(&h);
}
__device__ __forceinline__ float bfu(unsigned short u) {
  unsigned v = ((unsigned)u) << 16;
  return *reinterpret_cast<float*>(&v);
}

// ---------------------------------------------------------------------------
// Generic tiled fp32 GEMM (edge ops only): C[M,N] = A[M,K] @ W[K,N]
// EPI: 0 none, 1 +bias
// ---------------------------------------------------------------------------
template<int EPI>
__global__ __launch_bounds__(256) void gemm_f32(
    const float* __restrict__ A, int lda,
    const float* __restrict__ W, int ldw,
    const float* __restrict__ bias,
    float* __restrict__ C, int ldc,
    int M, int N, int K)
{
  __shared__ float As[BKt][BMt];
  __shared__ float Ws[BKt][BNt];
  const int tid = threadIdx.x;
  const int tx = tid & 15, ty = tid >> 4;
  const int m0 = blockIdx.y * BMt, n0 = blockIdx.x * BNt;
  const int am = tid >> 2, ak4 = (tid & 3) << 2;
  const int wk = tid >> 4, wn4 = (tid & 15) << 2;

  float acc[4][4] = {};

  for (int k0 = 0; k0 < K; k0 += BKt) {
    float4 va = make_float4(0.f, 0.f, 0.f, 0.f);
    {
      int m = m0 + am;
      if (m < M) {
        if (k0 + ak4 + 3 < K) {
          va = *reinterpret_cast<const float4*>(&A[(size_t)m * lda + k0 + ak4]);
        } else {
          float t[4];
          #pragma unroll
          for (int j = 0; j < 4; ++j)
            t[j] = (k0 + ak4 + j < K) ? A[(size_t)m * lda + k0 + ak4 + j] : 0.f;
          va = make_float4(t[0], t[1], t[2], t[3]);
        }
      }
    }
    As[ak4 + 0][am] = va.x;
    As[ak4 + 1][am] = va.y;
    As[ak4 + 2][am] = va.z;
    As[ak4 + 3][am] = va.w;

    float4 vw = make_float4(0.f, 0.f, 0.f, 0.f);
    {
      int kw = k0 + wk;
      if (kw < K) {
        if (n0 + wn4 + 3 < N) {
          vw = *reinterpret_cast<const float4*>(&W[(size_t)kw * ldw + n0 + wn4]);
        } else {
          float t[4];
          #pragma unroll
          for (int j = 0; j < 4; ++j)
            t[j] = (n0 + wn4 + j < N) ? W[(size_t)kw * ldw + n0 + wn4 + j] : 0.f;
          vw = make_float4(t[0], t[1], t[2], t[3]);
        }
      }
    }
    *reinterpret_cast<float4*>(&Ws[wk][wn4]) = vw;

    __syncthreads();
    #pragma unroll
    for (int kk = 0; kk < BKt; ++kk) {
      const float4 a4 = *reinterpret_cast<const float4*>(&As[kk][ty << 2]);
      const float4 w4 = *reinterpret_cast<const float4*>(&Ws[kk][tx << 2]);
      float av[4] = {a4.x, a4.y, a4.z, a4.w};
      float wv[4] = {w4.x, w4.y, w4.z, w4.w};
      #pragma unroll
      for (int i = 0; i < 4; ++i)
        #pragma unroll
        for (int j = 0; j < 4; ++j)
          acc[i][j] += av[i] * wv[j];
    }
    __syncthreads();
  }

  #pragma unroll
  for (int i = 0; i < 4; ++i) {
    int row = m0 + (ty << 2) + i;
    if (row >= M) continue;
    #pragma unroll
    for (int j = 0; j < 4; ++j) {
      int col = n0 + (tx << 2) + j;
      if (col >= N) continue;
      float v = acc[i][j];
      if (EPI == 1) v += bias[col];
      C[(size_t)row * ldc + col] = v;
    }
  }
}

// ---------------------------------------------------------------------------
// bf16 MFMA GEMM: A_bf16[M,K] @ WT_bf16[N,K] -> f32 C (EPI 0/3) or bf16 Cb
// (OBF=1). M,N,K multiples of 64.
// ---------------------------------------------------------------------------
template<int EPI, int OBF>
__global__ __launch_bounds__(256) void gemm_bf16(
    const __hip_bfloat16* __restrict__ A,   // [M][K]
    const __hip_bfloat16* __restrict__ WT,  // [N][K]
    const float* __restrict__ resid,
    float* __restrict__ C,
    __hip_bfloat16* __restrict__ Cb,
    int ldc, int M, int N, int K)
{
  __shared__ __align__(16) __hip_bfloat16 Asl[64][72];
  __shared__ __align__(16) __hip_bfloat16 Bsl[64][72];
  const int tid = threadIdx.x;
  const int wave = tid >> 6, lane = tid & 63;
  const int m0 = blockIdx.y * 64, n0 = blockIdx.x * 64;
  const int lrow = tid >> 2;
  const int lk   = (tid & 3) << 4;
  const int g16 = lane >> 4;
  const int l16 = lane & 15;

  f32x4 acc[4] = {};

  for (int k0 = 0; k0 < K; k0 += 64) {
    const uint4* ga = reinterpret_cast<const uint4*>(&A[(size_t)(m0 + lrow) * K + k0 + lk]);
    uint4* la = reinterpret_cast<uint4*>(&Asl[lrow][lk]);
    la[0] = ga[0]; la[1] = ga[1];
    const uint4* gb = reinterpret_cast<const uint4*>(&WT[(size_t)(n0 + lrow) * K + k0 + lk]);
    uint4* lb = reinterpret_cast<uint4*>(&Bsl[lrow][lk]);
    lb[0] = gb[0]; lb[1] = gb[1];
    __syncthreads();
    #pragma unroll
    for (int kk = 0; kk < 64; kk += 32) {
      bf16x8 a = *reinterpret_cast<const bf16x8*>(&Asl[wave * 16 + l16][kk + g16 * 8]);
      #pragma unroll
      for (int f = 0; f < 4; ++f) {
        bf16x8 b = *reinterpret_cast<const bf16x8*>(&Bsl[f * 16 + l16][kk + g16 * 8]);
        acc[f] = __builtin_amdgcn_mfma_f32_16x16x32_bf16(a, b, acc[f], 0, 0, 0);
      }
    }
    __syncthreads();
  }

  #pragma unroll
  for (int f = 0; f < 4; ++f) {
    #pragma unroll
    for (int r = 0; r < 4; ++r) {
      int row = m0 + wave * 16 + g16 * 4 + r;
      int col = n0 + f * 16 + l16;
      float v = acc[f][r];
      if (EPI == 3) v += resid[(size_t)row * ldc + col];
      if (OBF) Cb[(size_t)row * ldc + col] = __float2bfloat16(v);
      else     C[(size_t)row * ldc + col] = v;
    }
  }
}

// ---------------------------------------------------------------------------
// Batched bf16 MFMA GEMM (attention): per-z strides. C = A @ WT^T, f32 out.
// ---------------------------------------------------------------------------
__global__ __launch_bounds__(256) void gemm_bf16_bat(
    const __hip_bfloat16* __restrict__ A, size_t sA,
    const __hip_bfloat16* __restrict__ WT, size_t sW,
    float* __restrict__ C, size_t sC,
    int M, int N, int K)
{
  A  += (size_t)blockIdx.z * sA;
  WT += (size_t)blockIdx.z * sW;
  C  += (size_t)blockIdx.z * sC;
  __shared__ __align__(16) __hip_bfloat16 Asl[64][72];
  __shared__ __align__(16) __hip_bfloat16 Bsl[64][72];
  const int tid = threadIdx.x;
  const int wave = tid >> 6, lane = tid & 63;
  const int m0 = blockIdx.y * 64, n0 = blockIdx.x * 64;
  const int lrow = tid >> 2;
  const int lk   = (tid & 3) << 4;
  const int g16 = lane >> 4;
  const int l16 = lane & 15;

  f32x4 acc[4] = {};

  for (int k0 = 0; k0 < K; k0 += 64) {
    const uint4* ga = reinterpret_cast<const uint4*>(&A[(size_t)(m0 + lrow) * K + k0 + lk]);
    uint4* la = reinterpret_cast<uint4*>(&Asl[lrow][lk]);
    la[0] = ga[0]; la[1] = ga[1];
    const uint4* gb = reinterpret_cast<const uint4*>(&WT[(size_t)(n0 + lrow) * K + k0 + lk]);
    uint4* lb = reinterpret_cast<uint4*>(&Bsl[lrow][lk]);
    lb[0] = gb[0]; lb[1] = gb[1];
    __syncthreads();
    #pragma unroll
    for (int kk = 0; kk < 64; kk += 32) {
      bf16x8 a = *reinterpret_cast<const bf16x8*>(&Asl[wave * 16 + l16][kk + g16 * 8]);
      #pragma unroll
      for (int f = 0; f < 4; ++f) {
        bf16x8 b = *reinterpret_cast<const bf16x8*>(&Bsl[f * 16 + l16][kk + g16 * 8]);
        acc[f] = __builtin_amdgcn_mfma_f32_16x16x32_bf16(a, b, acc[f], 0, 0, 0);
      }
    }
    __syncthreads();
  }

  #pragma unroll
  for (int f = 0; f < 4; ++f) {
    #pragma unroll
    for (int r = 0; r < 4; ++r) {
      int row = m0 + wave * 16 + g16 * 4 + r;
      int col = n0 + f * 16 + l16;
      C[(size_t)row * N + col] = acc[f][r];
    }
  }
}

// ---------------------------------------------------------------------------
// Split-K x-proj with FUSED depthwise conv + SiLU (coalesced row loads).
// ---------------------------------------------------------------------------
__global__ __launch_bounds__(256) void xproj_conv_splitk(
    const __hip_bfloat16* __restrict__ xrb,  // [M][1536] bf16 (cols 0..768 = conv in)
    const float* __restrict__ cw,            // [768][4] layer slice
    const float* __restrict__ cb,            // [768]
    const __hip_bfloat16* __restrict__ WT,   // [64][768] padded xprojT slice
    float* __restrict__ part)                // [XPS][M][64]
{
  __shared__ __align__(16) __hip_bfloat16 Asl[64][72];
  __shared__ __align__(16) __hip_bfloat16 Bsl[64][72];
  const int tid = threadIdx.x;
  const int wave = tid >> 6, lane = tid & 63;
  const int split = blockIdx.x;
  const int m0 = blockIdx.y * 64;
  const int kbase = split * XPKC;
  const int lrow = tid >> 2;
  const int lk   = (tid & 3) << 4;
  const int g16 = lane >> 4;
  const int l16 = lane & 15;

  // --- fused conv+silu A-tile staging ---
  {
    const int m = m0 + lrow;
    const int b = m >> 9, l = m & 511;
    const int dcol0 = kbase + lk;
    unsigned wrow[4][8];
    #pragma unroll
    for (int k = 0; k < 4; ++k) {
      int t = l - 3 + k;
      if (t >= 0) {
        const uint4* p = reinterpret_cast<const uint4*>(
            &xrb[((size_t)(b * LL + t)) * (2 * D_INNER) + dcol0]);
        uint4 q0 = p[0], q1 = p[1];
        wrow[k][0] = q0.x; wrow[k][1] = q0.y; wrow[k][2] = q0.z; wrow[k][3] = q0.w;
        wrow[k][4] = q1.x; wrow[k][5] = q1.y; wrow[k][6] = q1.z; wrow[k][7] = q1.w;
      } else {
        #pragma unroll
        for (int w = 0; w < 8; ++w) wrow[k][w] = 0u;
      }
    }
    #pragma unroll
    for (int j = 0; j < 16; ++j) {
      float4 cw4 = *reinterpret_cast<const float4*>(&cw[(size_t)(dcol0 + j) * 4]);
      float cwa[4] = {cw4.x, cw4.y, cw4.z, cw4.w};
      float a = cb[dcol0 + j];
      #pragma unroll
      for (int k = 0; k < 4; ++k) {
        unsigned w = wrow[k][j >> 1];
        unsigned short hv = (j & 1) ? (unsigned short)(w >> 16) : (unsigned short)(w & 0xffff);
        a += bfu(hv) * cwa[k];
      }
      Asl[lrow][lk + j] = __float2bfloat16(silu_f(a));
    }
  }

  const uint4* gb = reinterpret_cast<const uint4*>(&WT[(size_t)lrow * D_INNER + kbase + lk]);
  uint4* lb = reinterpret_cast<uint4*>(&Bsl[lrow][lk]);
  lb[0] = gb[0]; lb[1] = gb[1];
  __syncthreads();

  f32x4 acc[4] = {};
  #pragma unroll
  for (int kk = 0; kk < 64; kk += 32) {
    bf16x8 a = *reinterpret_cast<const bf16x8*>(&Asl[wave * 16 + l16][kk + g16 * 8]);
    #pragma unroll
    for (int f = 0; f < 4; ++f) {
      bf16x8 b = *reinterpret_cast<const bf16x8*>(&Bsl[f * 16 + l16][kk + g16 * 8]);
      acc[f] = __builtin_amdgcn_mfma_f32_16x16x32_bf16(a, b, acc[f], 0, 0, 0);
    }
  }

  #pragma unroll
  for (int f = 0; f < 4; ++f) {
    #pragma unroll
    for (int r = 0; r < 4; ++r) {
      int row = m0 + wave * 16 + g16 * 4 + r;
      int col = f * 16 + l16;
      part[((size_t)split * MTOK + row) * 64 + col] = acc[f][r];
    }
  }
}

__global__ __launch_bounds__(256) void xproj_reduce_kernel(
    const float* __restrict__ part, float* __restrict__ xdbl)
{
  int idx = blockIdx.x * 256 + threadIdx.x;
  if (idx >= MTOK * XP_N) return;
  int m = idx / XP_N, col = idx - m * XP_N;
  float s = 0.f;
  #pragma unroll
  for (int p = 0; p < XPS; ++p)
    s += part[((size_t)p * MTOK + m) * 64 + col];
  xdbl[idx] = s;
}

// ---------------------------------------------------------------------------
// Weight convert + transpose: src f32 [L][K][N] -> dst bf16 [L][N][K]
// ---------------------------------------------------------------------------
__global__ __launch_bounds__(256) void wconv_t_kernel(
    const float* __restrict__ src, __hip_bfloat16* __restrict__ dst,
    int K, int N, size_t ldl)
{
  __shared__ float tile[32][33];
  int l = blockIdx.z;
  int kb = blockIdx.y * 32, nb = blockIdx.x * 32;
  int tn = threadIdx.x & 31, tk = threadIdx.x >> 5;  // 32 x 8
  const float* s = src + (size_t)l * K * N;
  __hip_bfloat16* dd = dst + (size_t)l * ldl;
  #pragma unroll
  for (int i = 0; i < 4; ++i) {
    int k = kb + tk + i * 8, n = nb + tn;
    tile[tk + i * 8][tn] = (k < K && n < N) ? s[(size_t)k * N + n] : 0.f;
  }
  __syncthreads();
  #pragma unroll
  for (int i = 0; i < 4; ++i) {
    int n = nb + tk + i * 8, k = kb + tn;
    if (n < N && k < K) dd[(size_t)n * K + k] = __float2bfloat16(tile[tn][tk + i * 8]);
  }
}

// ---------------------------------------------------------------------------
// f32 -> bf16 elementwise convert (n multiple of 4)
// ---------------------------------------------------------------------------
__global__ __launch_bounds__(256) void f2b_kernel(
    const float* __restrict__ src, __hip_bfloat16* __restrict__ dst, int n)
{
  int i = (blockIdx.x * 256 + threadIdx.x) * 4;
  if (i >= n) return;
  float4 v = *reinterpret_cast<const float4*>(&src[i]);
  bf16x4 o;
  o[0] = bf_raw(v.x); o[1] = bf_raw(v.y); o[2] = bf_raw(v.z); o[3] = bf_raw(v.w);
  *reinterpret_cast<bf16x4*>(&dst[i]) = o;
}

// ---------------------------------------------------------------------------
// Row softmax: scores f32 [R][512] -> P bf16 [R][512]; one wave per row.
// ---------------------------------------------------------------------------
__global__ __launch_bounds__(256) void softmax_rows_kernel(
    const float* __restrict__ scores, __hip_bfloat16* __restrict__ P)
{
  int row = (blockIdx.x * 256 + threadIdx.x) >> 6;
  int lane = threadIdx.x & 63;
  if (row >= BB * LL) return;
  const float* s = scores + (size_t)row * LL + lane * 8;
  float4 v0 = *reinterpret_cast<const float4*>(s);
  float4 v1 = *reinterpret_cast<const float4*>(s + 4);
  float mx = fmaxf(fmaxf(fmaxf(v0.x, v0.y), fmaxf(v0.z, v0.w)),
                   fmaxf(fmaxf(v1.x, v1.y), fmaxf(v1.z, v1.w)));
  #pragma unroll
  for (int off = 32; off; off >>= 1) mx = fmaxf(mx, __shfl_xor(mx, off, 64));
  float e[8];
  e[0] = __expf(v0.x - mx); e[1] = __expf(v0.y - mx);
  e[2] = __expf(v0.z - mx); e[3] = __expf(v0.w - mx);
  e[4] = __expf(v1.x - mx); e[5] = __expf(v1.y - mx);
  e[6] = __expf(v1.z - mx); e[7] = __expf(v1.w - mx);
  float sum = ((e[0] + e[1]) + (e[2] + e[3])) + ((e[4] + e[5]) + (e[6] + e[7]));
  #pragma unroll
  for (int off = 32; off; off >>= 1) sum += __shfl_xor(sum, off, 64);
  float inv = 1.f / sum;
  bf16x8 o;
  #pragma unroll
  for (int j = 0; j < 8; ++j) o[j] = bf_raw(e[j] * inv);
  *reinterpret_cast<bf16x8*>(&P[(size_t)row * LL + lane * 8]) = o;
}

// ---------------------------------------------------------------------------
// RMSNorm: one wave per row; fp32 output optional
// ---------------------------------------------------------------------------
__global__ __launch_bounds__(256) void rmsnorm_kernel(
    const float* __restrict__ x, const float* __restrict__ w,
    float* __restrict__ out, __hip_bfloat16* __restrict__ outb, int M, int N)
{
  int gw = (blockIdx.x * blockDim.x + threadIdx.x) >> 6;
  int lane = threadIdx.x & 63;
  if (gw >= M) return;
  const float* row = x + (size_t)gw * N;
  float ss = 0.f;
  for (int j = lane; j < N; j += 64) { float v = row[j]; ss += v * v; }
  #pragma unroll
  for (int off = 32; off; off >>= 1) ss += __shfl_xor(ss, off, 64);
  float scale = rsqrtf(ss / (float)N + 1e-5f);
  float* orow = out ? out + (size_t)gw * N : nullptr;
  __hip_bfloat16* brow = outb + (size_t)gw * N;
  for (int j = lane; j < N; j += 64) {
    float v = row[j] * scale * w[j];
    if (orow) orow[j] = v;
    brow[j] = __float2bfloat16(v);
  }
}

// ---------------------------------------------------------------------------
// Chunked parallel selective scan v10: conv fused but with 1-load staging.
// Stage A loads the packed xr word (1 global load/thread) into LDS (aliased
// over the dead-until-phase-3 sY buffer) + computes sdelta; barrier; stage B
// computes conv+silu from LDS neighbors sxr[l..l+3] (zero extra global
// traffic vs v8). Otherwise identical to v8.
// ---------------------------------------------------------------------------
#define SC6_T  16
#define SC6_NC 32
__global__ __launch_bounds__(512) void scan_kernel10(
    const __hip_bfloat16* __restrict__ xrb, // M x 1536 bf16 (conv in cols 0..768, res cols 768..)
    const float* __restrict__ xdbl,   // M x 56 (dt|B|C)
    const float* __restrict__ A_log,  // 768 x 16 (layer slice)
    const float* __restrict__ Dp,     // 768
    const float* __restrict__ dtw,    // [24][768] layer slice
    const float* __restrict__ dtb,    // [768] layer slice
    const float* __restrict__ cw,     // [768][4] layer slice
    const float* __restrict__ cb,     // [768]
    __hip_bfloat16* __restrict__ yg)  // M x 768 bf16
{
  __shared__ float sdelta[2][LL];
  __shared__ unsigned supk[LL];            // packed bf16 pair (u_d0, u_d1)
  __shared__ float sdw[2][DT_RANK];
  __shared__ float sP[2][SC6_NC][D_STATE + 1];
  __shared__ float sS[2][SC6_NC][D_STATE + 1];
  __shared__ float sH0[2][SC6_NC][D_STATE + 1];
  __shared__ float sY[2][LL][5];

  // alias the conv staging buffer over sY (dead until phase 3)
  unsigned* sxr = reinterpret_cast<unsigned*>(&sY[0][0][0]);  // [LL+3]

  const int id = blockIdx.x;
  const int r  = id / 48;        // 0..31
  const int G  = id % 48;        // id%8 == G%8
  const int b  = G / 12;         // 0..3
  const int q  = G % 12;
  const int d0 = q * 64 + 2 * r;
  const int d1 = d0 + 1;

  const int tid = threadIdx.x;   // 0..511
  const int n = tid & 15;
  const int c = tid >> 4;        // 0..31

  if (tid < DT_RANK) {
    sdw[0][tid] = dtw[tid * D_INNER + d0];
    sdw[1][tid] = dtw[tid * D_INNER + d1];
  }
  if (tid < 3) sxr[tid] = 0u;    // rows -3..-1 are zero (causal pad)
  __syncthreads();

  // Stage A: one l per thread — dt-proj dot + single packed xr load
  {
    const int l = tid;
    const size_t m = (size_t)(b * LL + l);
    float acc0 = dtb[d0], acc1 = dtb[d1];
    const float* xrow = &xdbl[m * 56];
    #pragma unroll
    for (int k4 = 0; k4 < DT_RANK; k4 += 4) {
      float4 xv = *reinterpret_cast<const float4*>(&xrow[k4]);
      acc0 += xv.x * sdw[0][k4] + xv.y * sdw[0][k4 + 1] + xv.z * sdw[0][k4 + 2] + xv.w * sdw[0][k4 + 3];
      acc1 += xv.x * sdw[1][k4] + xv.y * sdw[1][k4 + 1] + xv.z * sdw[1][k4 + 2] + xv.w * sdw[1][k4 + 3];
    }
    sdelta[0][l] = (acc0 > 20.f) ? acc0 : log1pf(__expf(acc0));
    sdelta[1][l] = (acc1 > 20.f) ? acc1 : log1pf(__expf(acc1));
    sxr[3 + l] = *reinterpret_cast<const unsigned*>(&xrb[m * (2 * D_INNER) + d0]);
  }
  __syncthreads();

  // Stage B: conv+silu from LDS neighbors -> packed u
  {
    const int l = tid;
    float4 cw0 = *reinterpret_cast<const float4*>(&cw[(size_t)d0 * 4]);
    float4 cw1 = *reinterpret_cast<const float4*>(&cw[(size_t)d1 * 4]);
    float cwa0[4] = {cw0.x, cw0.y, cw0.z, cw0.w};
    float cwa1[4] = {cw1.x, cw1.y, cw1.z, cw1.w};
    float u0 = cb[d0], u1 = cb[d1];
    #pragma unroll
    for (int k = 0; k < 4; ++k) {
      unsigned w = sxr[l + k];                 // row l-3+k
      u0 += bfu((unsigned short)(w & 0xffff)) * cwa0[k];
      u1 += bfu((unsigned short)(w >> 16)) * cwa1[k];
    }
    unsigned pk = ((unsigned)(unsigned short)bf_raw(silu_f(u0))) |
                  (((unsigned)(unsigned short)bf_raw(silu_f(u1))) << 16);
    supk[l] = pk;
  }

  const float Aval0 = -__expf(A_log[d0 * D_STATE + n]);
  const float Aval1 = -__expf(A_log[d1 * D_STATE + n]);
  const int l0 = c * SC6_T;
  const size_t mbase = (size_t)(b * LL + l0);

  // B prefetch: 16 loads shared by both d's
  float Bv_s[SC6_T];
  #pragma unroll
  for (int t = 0; t < SC6_T; ++t)
    Bv_s[t] = xdbl[(mbase + t) * 56 + DT_RANK + n];

  __syncthreads();

  // Phase 1: per-chunk affine composition for both d's; stash a only
  float a_s[2][SC6_T];
  {
    float P0 = 1.f, S0 = 0.f, P1 = 1.f, S1 = 0.f;
    #pragma unroll
    for (int t = 0; t < SC6_T; ++t) {
      int l = l0 + t;
      unsigned uu = supk[l];
      float uv0 = bfu((unsigned short)(uu & 0xffff));
      float uv1 = bfu((unsigned short)(uu >> 16));
      float dv0 = sdelta[0][l];
      float dv1 = sdelta[1][l];
      float a0 = __expf(dv0 * Aval0);
      float a1 = __expf(dv1 * Aval1);
      P0 *= a0; S0 = a0 * S0 + (dv0 * Bv_s[t]) * uv0;
      P1 *= a1; S1 = a1 * S1 + (dv1 * Bv_s[t]) * uv1;
      a_s[0][t] = a0; a_s[1][t] = a1;
    }
    sP[0][c][n] = P0; sS[0][c][n] = S0;
    sP[1][c][n] = P1; sS[1][c][n] = S1;
  }

  // C prefetch: loads fly during phase 2 + barriers
  float Cv_s[SC6_T];
  #pragma unroll
  for (int t = 0; t < SC6_T; ++t)
    Cv_s[t] = xdbl[(mbase + t) * 56 + DT_RANK + D_STATE + n];

  __syncthreads();

  // Phase 2: Kogge-Stone over 32 chunks, both d's, all 512 threads
  {
    const int c2 = tid & 31;
    const int n2 = tid >> 5;
    #pragma unroll
    for (int dd = 0; dd < 2; ++dd) {
      float p = sP[dd][c2][n2];
      float s = sS[dd][c2][n2];
      #pragma unroll
      for (int k = 1; k <= 16; k <<= 1) {
        float pp = __shfl_up(p, k, 64);
        float sp = __shfl_up(s, k, 64);
        if (c2 >= k) { s = p * sp + s; p = p * pp; }
      }
      if (c2 == 0) sH0[dd][0][n2] = 0.f;
      if (c2 < 31) sH0[dd][c2 + 1][n2] = s;
    }
  }
  __syncthreads();

  // Phase 3: dual replay; dbu recomputed from LDS; 2-shfl partial reduce
  {
    float h0 = sH0[0][c][n];
    float h1 = sH0[1][c][n];
    #pragma unroll
    for (int t = 0; t < SC6_T; ++t) {
      int l = l0 + t;
      unsigned uu = supk[l];
      float uv0 = bfu((unsigned short)(uu & 0xffff));
      float uv1 = bfu((unsigned short)(uu >> 16));
      float dv0 = sdelta[0][l];
      float dv1 = sdelta[1][l];
      h0 = a_s[0][t] * h0 + (dv0 * Bv_s[t]) * uv0;
      h1 = a_s[1][t] * h1 + (dv1 * Bv_s[t]) * uv1;
      float c0 = h0 * Cv_s[t];
      float c1 = h1 * Cv_s[t];
      c0 += __shfl_xor(c0, 1, 64); c0 += __shfl_xor(c0, 2, 64);
      c1 += __shfl_xor(c1, 1, 64); c1 += __shfl_xor(c1, 2, 64);
      if ((n & 3) == 0) { sY[0][l][n >> 2] = c0; sY[1][l][n >> 2] = c1; }
    }
  }
  __syncthreads();

  // Final: one l per thread — both d's, paired bf16 gate read + packed write
  {
    const int l = tid;
    const size_t m = (size_t)(b * LL + l);
    unsigned uu = supk[l];
    float uv0 = bfu((unsigned short)(uu & 0xffff));
    float uv1 = bfu((unsigned short)(uu >> 16));
    float y0 = (sY[0][l][0] + sY[0][l][1]) + (sY[0][l][2] + sY[0][l][3]) + uv0 * Dp[d0];
    float y1 = (sY[1][l][0] + sY[1][l][1]) + (sY[1][l][2] + sY[1][l][3]) + uv1 * Dp[d1];
    unsigned rr = *reinterpret_cast<const unsigned*>(&xrb[m * (2 * D_INNER) + D_INNER + d0]);
    float r0 = bfu((unsigned short)(rr & 0xffff));
    float r1 = bfu((unsigned short)(rr >> 16));
    y0 *= silu_f(r0);
    y1 *= silu_f(r1);
    unsigned outw = ((unsigned)(unsigned short)bf_raw(y0)) |
                    (((unsigned)(unsigned short)bf_raw(y1)) << 16);
    *reinterpret_cast<unsigned*>(&yg[m * D_INNER + d0]) = outw;
  }
}

// ---------------------------------------------------------------------------
extern "C" void kernel_launch(void* const* d_in, const int* in_sizes, int n_in,
                              void* d_out, int out_size, void* d_ws, size_t ws_size,
                              hipStream_t stream) {
  const float* x        = (const float*)d_in[0];
  const float* enc      = (const float*)d_in[1];
  const float* w_in     = (const float*)d_in[2];
  const float* b_in     = (const float*)d_in[3];
  const float* ln_w     = (const float*)d_in[4];
  const float* inproj_w = (const float*)d_in[5];
  const float* conv_w   = (const float*)d_in[6];
  const float* conv_b   = (const float*)d_in[7];
  const float* xproj_w  = (const float*)d_in[8];
  const float* dtproj_w = (const float*)d_in[9];
  const float* dtproj_b = (const float*)d_in[10];
  const float* A_log    = (const float*)d_in[11];
  const float* Dvec     = (const float*)d_in[12];
  const float* outproj_w= (const float*)d_in[13];
  const float* normf_w  = (const float*)d_in[14];
  const float* w_out    = (const float*)d_in[15];

  float* ws = (float*)d_ws;
  float* h     = ws; ws += MTOK * D_MODEL;
  float* hn    = ws; ws += MTOK * D_MODEL;
  float* xdbl  = ws; ws += MTOK * XP_N;
  float* xpart = ws; ws += XPS * MTOK * 64;
  float* h2    = ws; ws += MTOK * D_MODEL;
  float* scores= ws; ws += BB * LL * LL;
  __hip_bfloat16* xr_bf = (__hip_bfloat16*)ws; ws += MTOK * 2 * D_INNER / 2;
  __hip_bfloat16* hn_bf = (__hip_bfloat16*)ws; ws += MTOK * D_MODEL / 2;
  __hip_bfloat16* yg_bf = (__hip_bfloat16*)ws; ws += MTOK * D_INNER / 2;
  __hip_bfloat16* h_bf  = (__hip_bfloat16*)ws; ws += MTOK * D_MODEL / 2;
  __hip_bfloat16* P_bf  = (__hip_bfloat16*)ws; ws += BB * LL * LL / 2;
  __hip_bfloat16* enc_bf= (__hip_bfloat16*)ws; ws += BB * LL * D_MODEL / 2;
  __hip_bfloat16* encT  = (__hip_bfloat16*)ws; ws += BB * LL * D_MODEL / 2;
  __hip_bfloat16* WinT  = (__hip_bfloat16*)ws; ws += N_LAYER * D_MODEL * 2 * D_INNER / 2;
  __hip_bfloat16* WoutT = (__hip_bfloat16*)ws; ws += N_LAYER * D_INNER * D_MODEL / 2;
  __hip_bfloat16* XpT   = (__hip_bfloat16*)ws; ws += N_LAYER * 64 * D_INNER / 2;

  dim3 blk256(256), blk512(512);

  // Prologue: weight conversions
  wconv_t_kernel<<<dim3(2 * D_INNER / 32, D_MODEL / 32, N_LAYER), blk256, 0, stream>>>(
      inproj_w, WinT, D_MODEL, 2 * D_INNER, (size_t)2 * D_INNER * D_MODEL);
  wconv_t_kernel<<<dim3(D_MODEL / 32, D_INNER / 32, N_LAYER), blk256, 0, stream>>>(
      outproj_w, WoutT, D_INNER, D_MODEL, (size_t)D_MODEL * D_INNER);
  wconv_t_kernel<<<dim3((XP_N + 31) / 32, D_INNER / 32, N_LAYER), blk256, 0, stream>>>(
      xproj_w, XpT, D_INNER, XP_N, (size_t)64 * D_INNER);
  // enc conversions for attention
  f2b_kernel<<<(BB * LL * D_MODEL / 4 + 255) / 256, blk256, 0, stream>>>(
      enc, enc_bf, BB * LL * D_MODEL);
  wconv_t_kernel<<<dim3(D_MODEL / 32, LL / 32, BB), blk256, 0, stream>>>(
      enc, encT, LL, D_MODEL, (size_t)D_MODEL * LL);

  // input projection: h = x @ w_in + b_in  (fp32)
  gemm_f32<1><<<dim3(D_MODEL / BNt, MTOK / BMt), blk256, 0, stream>>>(
      x, N_MELS, w_in, D_MODEL, b_in, h, D_MODEL, MTOK, D_MODEL, N_MELS);

  auto mamba = [&](float* hcur, int i) {
    rmsnorm_kernel<<<MTOK * 64 / 256, blk256, 0, stream>>>(
        hcur, ln_w + (size_t)i * D_MODEL, nullptr, hn_bf, MTOK, D_MODEL);
    // in-proj (bf16 MFMA) -> bf16 xr
    gemm_bf16<0, 1><<<dim3(2 * D_INNER / 64, MTOK / 64), blk256, 0, stream>>>(
        hn_bf, WinT + (size_t)i * D_MODEL * 2 * D_INNER, nullptr,
        nullptr, xr_bf, 2 * D_INNER, MTOK, 2 * D_INNER, D_MODEL);
    // x-proj with fused conv+silu
    xproj_conv_splitk<<<dim3(XPS, MTOK / 64), blk256, 0, stream>>>(
        xr_bf, conv_w + (size_t)i * D_INNER * D_CONV, conv_b + (size_t)i * D_INNER,
        XpT + (size_t)i * 64 * D_INNER, xpart);
    xproj_reduce_kernel<<<(MTOK * XP_N + 255) / 256, blk256, 0, stream>>>(xpart, xdbl);
    // scan with LDS-staged fused conv
    scan_kernel10<<<BB * D_INNER / 2, blk512, 0, stream>>>(
        xr_bf, xdbl, A_log + (size_t)i * D_INNER * D_STATE, Dvec + (size_t)i * D_INNER,
        dtproj_w + (size_t)i * DT_RANK * D_INNER, dtproj_b + (size_t)i * D_INNER,
        conv_w + (size_t)i * D_INNER * D_CONV, conv_b + (size_t)i * D_INNER,
        yg_bf);
    gemm_bf16<3, 0><<<dim3(D_MODEL / 64, MTOK / 64), blk256, 0, stream>>>(
        yg_bf, WoutT + (size_t)i * D_INNER * D_MODEL, hcur,
        hcur, nullptr, D_MODEL, MTOK, D_MODEL, D_INNER);
  };

  for (int i = 0; i < N_LAYER / 2; ++i) mamba(h, i);

  // ---- attention via MFMA ----
  f2b_kernel<<<(MTOK * D_MODEL / 4 + 255) / 256, blk256, 0, stream>>>(
      h, h_bf, MTOK * D_MODEL);
  gemm_bf16_bat<<<dim3(LL / 64, LL / 64, BB), blk256, 0, stream>>>(
      h_bf, (size_t)LL * D_MODEL, enc_bf, (size_t)LL * D_MODEL,
      scores, (size_t)LL * LL, LL, LL, D_MODEL);
  softmax_rows_kernel<<<(BB * LL * 64) / 256, blk256, 0, stream>>>(scores, P_bf);
  gemm_bf16_bat<<<dim3(D_MODEL / 64, LL / 64, BB), blk256, 0, stream>>>(
      P_bf, (size_t)LL * LL, encT, (size_t)D_MODEL * LL,
      h2, (size_t)LL * D_MODEL, LL, D_MODEL, LL);

  for (int i = N_LAYER / 2; i < N_LAYER; ++i) mamba(h2, i);

  rmsnorm_kernel<<<MTOK * 64 / 256, blk256, 0, stream>>>(h2, normf_w, hn, hn_bf, MTOK, D_MODEL);
  gemm_f32<0><<<dim3((N_MELS + BNt - 1) / BNt, MTOK / BMt), blk256, 0, stream>>>(
      hn, D_MODEL, w_out, N_MELS, nullptr, (float*)d_out, N_MELS, MTOK, N_MELS, D_MODEL);
}